// Round 1
// baseline (187.005 us; speedup 1.0000x reference)
//
#include <hip/hip_runtime.h>
#include <hip/hip_bf16.h>
#include <stdint.h>

// Problem constants (match reference)
#define B_SZ 8
#define T_LEN 1024
#define C_DIM 1024
#define M_ROWS (B_SZ * T_LEN)   // 8192
#define NCH 16
#define CHL (T_LEN / NCH)       // 64

typedef unsigned short ushort_t;
typedef __attribute__((ext_vector_type(8))) short short8;
typedef __attribute__((ext_vector_type(4))) float f32x4;

static __device__ __forceinline__ float bf2f(ushort_t u) {
  union { unsigned int i; float f; } x; x.i = ((unsigned int)u) << 16; return x.f;
}
static __device__ __forceinline__ ushort_t f2bf(float f) {
  union { float f; unsigned int i; } x; x.f = f;
  unsigned int r = x.i + 0x7fffu + ((x.i >> 16) & 1u);
  return (ushort_t)(r >> 16);
}

static __device__ __forceinline__ void gload_lds16(const void* g, void* l) {
  __builtin_amdgcn_global_load_lds(
      (const __attribute__((address_space(1))) void*)g,
      (__attribute__((address_space(3))) void*)l, 16, 0, 0);
}

// ---------------- weight f32 -> bf16 conversion (4 x 1M elements) ----------
__global__ void cvt_w_kernel(const float* __restrict__ wk, const float* __restrict__ wv,
                             const float* __restrict__ wr, const float* __restrict__ wo,
                             ushort_t* __restrict__ out) {
  int gid = blockIdx.x * 256 + threadIdx.x;       // 0 .. 4*2^20-1
  int which = gid >> 20;
  int off = gid & ((1 << 20) - 1);
  const float* src = which == 0 ? wk : which == 1 ? wv : which == 2 ? wr : wo;
  out[gid] = f2bf(src[off]);
}

// ---------------- time-shift mixing -> bf16 xm -----------------------------
__global__ void xm_kernel(const float* __restrict__ x, const float* __restrict__ tm,
                          const float* __restrict__ cm, ushort_t* __restrict__ xmb) {
  int gid = blockIdx.x * 256 + threadIdx.x;       // over B*T*C
  int c = gid & (C_DIM - 1);
  int t = (gid >> 10) & (T_LEN - 1);
  float xv = x[gid];
  float xprev = (t > 0) ? x[gid - C_DIM] : 0.f;
  float xnext = (t < T_LEN - 1) ? x[gid + C_DIM] : 0.f;
  float xc = (c < C_DIM / 2) ? xprev : xnext;
  float tmc = tm[c], cmc = cm[c];
  float v = xv * tmc + xprev * (1.f - tmc) + xc * cmc;
  xmb[gid] = f2bf(v);
}

// ---------------- bf16 NT GEMM: out[m,n] = sum_k A[m,k]*Bw[n,k] ------------
// MODE 0: k-proj  -> f32 out = exp(min(v,60))
// MODE 1: v-proj  -> bf16 out
// MODE 2: r-proj  -> bf16 out = sigmoid(v)
// MODE 3: o-proj  -> f32 out (d_out)
template <int MODE>
__global__ __launch_bounds__(256) void gemm_bt(const ushort_t* __restrict__ A,
                                               const ushort_t* __restrict__ Bw,
                                               void* __restrict__ Cvoid,
                                               int M, int N, int K) {
  __shared__ ushort_t As[128 * 32];
  __shared__ ushort_t Bs[128 * 32];
  const int tid = threadIdx.x;
  const int lane = tid & 63;
  const int bm = blockIdx.x * 128;
  const int bn = blockIdx.y * 128;
  const int wave = tid >> 6;
  const int wr = (wave >> 1) * 64;   // wave row offset in tile
  const int wc = (wave & 1) * 64;    // wave col offset in tile

  f32x4 acc[4][4];
#pragma unroll
  for (int m = 0; m < 4; ++m)
#pragma unroll
    for (int n = 0; n < 4; ++n) acc[m][n] = (f32x4){0.f, 0.f, 0.f, 0.f};

  const int srow = tid >> 2;           // 0..63
  const int scol = (tid & 3) * 8;      // 0,8,16,24  (elements)
  const ushort_t* Ag = A + (size_t)(bm + srow) * K + scol;
  const ushort_t* Bg = Bw + (size_t)(bn + srow) * K + scol;
  ushort_t* AsP = &As[tid * 8];        // linear: lds dest = wave base + lane*16B
  ushort_t* BsP = &Bs[tid * 8];

  const int ksub = (lane >> 4) * 8;
  const int fr = lane & 15;

  for (int k0 = 0; k0 < K; k0 += 32) {
    __syncthreads();
    gload_lds16(Ag + k0, AsP);
    gload_lds16(Ag + (size_t)64 * K + k0, AsP + 64 * 32);
    gload_lds16(Bg + k0, BsP);
    gload_lds16(Bg + (size_t)64 * K + k0, BsP + 64 * 32);
    asm volatile("s_waitcnt vmcnt(0)" ::: "memory");
    __syncthreads();
    short8 af[4], bfr[4];
#pragma unroll
    for (int m = 0; m < 4; ++m)
      af[m] = *(const short8*)&As[(wr + m * 16 + fr) * 32 + ksub];
#pragma unroll
    for (int n = 0; n < 4; ++n)
      bfr[n] = *(const short8*)&Bs[(wc + n * 16 + fr) * 32 + ksub];
#pragma unroll
    for (int m = 0; m < 4; ++m)
#pragma unroll
      for (int n = 0; n < 4; ++n)
        acc[m][n] = __builtin_amdgcn_mfma_f32_16x16x32_bf16(af[m], bfr[n], acc[m][n], 0, 0, 0);
  }

  const int crow0 = (lane >> 4) * 4;   // C/D layout: col=lane&15, row=(lane>>4)*4+j
#pragma unroll
  for (int m = 0; m < 4; ++m)
#pragma unroll
    for (int n = 0; n < 4; ++n)
#pragma unroll
      for (int j = 0; j < 4; ++j) {
        float v = acc[m][n][j];
        size_t idx = (size_t)(bm + wr + m * 16 + crow0 + j) * N + (bn + wc + n * 16 + fr);
        if (MODE == 0) {
          ((float*)Cvoid)[idx] = __expf(fminf(v, 60.f));
        } else if (MODE == 1) {
          ((ushort_t*)Cvoid)[idx] = f2bf(v);
        } else if (MODE == 2) {
          ((ushort_t*)Cvoid)[idx] = f2bf(1.f / (1.f + __expf(-v)));
        } else {
          ((float*)Cvoid)[idx] = v;
        }
      }
}

// ---------------- wkv chunked scan -----------------------------------------
// Phase A: per (b, chunk, c) compute chunk-local (a, b, p) from zero init.
__global__ void wkv_phaseA(const float* __restrict__ kk, const ushort_t* __restrict__ vv,
                           const float* __restrict__ td,
                           float* __restrict__ sa, float* __restrict__ sb,
                           float* __restrict__ sp) {
  int gid = blockIdx.x * 256 + threadIdx.x;   // b*NCH*C + ch*C + c
  int c = gid & (C_DIM - 1);
  int ch = (gid >> 10) & (NCH - 1);
  int b = gid >> 14;
  float w = td[c] * (1.f / T_LEN);
  size_t base = ((size_t)b * T_LEN + ch * CHL) * C_DIM + c;
  float a = 0.f, bb = 0.f, p = -1e38f;
  for (int t = 0; t < CHL; ++t) {
    float kt = kk[base + (size_t)t * C_DIM];
    float vt = bf2f(vv[base + (size_t)t * C_DIM]);
    float no2 = fmaxf(w + p, kt);
    float e1 = __expf(w + p - no2);
    float e2 = __expf(kt - no2);
    a = e1 * a + e2 * vt;
    bb = e1 * bb + e2;
    p = no2;
  }
  sa[gid] = a; sb[gid] = bb; sp[gid] = p;
}

// Phase B: per (b,c) serial prefix over the 16 chunk states; overwrite each
// chunk slot with its INCOMING state (state before the chunk).
__global__ void wkv_phaseB(const float* __restrict__ td,
                           float* __restrict__ sa, float* __restrict__ sb,
                           float* __restrict__ sp) {
  int gid = blockIdx.x * 256 + threadIdx.x;   // b*C + c
  int c = gid & (C_DIM - 1);
  int b = gid >> 10;
  float wL = td[c] * (1.f / T_LEN) * (float)CHL;
  float a = 0.f, bb = 0.f, p = -1e38f;
  for (int ch = 0; ch < NCH; ++ch) {
    size_t idx = ((size_t)b * NCH + ch) * C_DIM + c;
    float ac = sa[idx], bc = sb[idx], pc = sp[idx];
    sa[idx] = a; sb[idx] = bb; sp[idx] = p;
    float pn = fmaxf(p + wL, pc);
    float e1 = __expf(p + wL - pn);
    float e2 = __expf(pc - pn);
    a = e1 * a + e2 * ac;
    bb = e1 * bb + e2 * bc;
    p = pn;
  }
}

// Phase C: per (b, chunk, c): rerun scan from incoming state, emit
// sy = bf16( sigmoid(r) * y ).
__global__ void wkv_phaseC(const float* __restrict__ kk, const ushort_t* __restrict__ vv,
                           const ushort_t* __restrict__ sr, const float* __restrict__ td,
                           const float* __restrict__ tf,
                           const float* __restrict__ sa, const float* __restrict__ sb,
                           const float* __restrict__ sp, ushort_t* __restrict__ sy) {
  int gid = blockIdx.x * 256 + threadIdx.x;
  int c = gid & (C_DIM - 1);
  int ch = (gid >> 10) & (NCH - 1);
  int b = gid >> 14;
  float w = td[c] * (1.f / T_LEN);
  float u = tf[c] * (1.f / T_LEN);
  size_t base = ((size_t)b * T_LEN + ch * CHL) * C_DIM + c;
  float a = sa[gid], bb = sb[gid], p = sp[gid];
  for (int t = 0; t < CHL; ++t) {
    float kt = kk[base + (size_t)t * C_DIM];
    float vt = bf2f(vv[base + (size_t)t * C_DIM]);
    // read: y uses pre-update state with u-boost
    float no = fmaxf(p, u + kt);
    float e1 = __expf(p - no);
    float e2 = __expf(u + kt - no);
    float y = (e1 * a + e2 * vt) / (e1 * bb + e2);
    float srv = bf2f(sr[base + (size_t)t * C_DIM]);
    sy[base + (size_t)t * C_DIM] = f2bf(srv * y);
    // state update
    float no2 = fmaxf(w + p, kt);
    e1 = __expf(w + p - no2);
    e2 = __expf(kt - no2);
    a = e1 * a + e2 * vt;
    bb = e1 * bb + e2;
    p = no2;
  }
}

// ---------------------------------------------------------------------------
extern "C" void kernel_launch(void* const* d_in, const int* in_sizes, int n_in,
                              void* d_out, int out_size, void* d_ws, size_t ws_size,
                              hipStream_t stream) {
  const float* x  = (const float*)d_in[0];
  const float* td = (const float*)d_in[1];
  const float* tf = (const float*)d_in[2];
  const float* tm = (const float*)d_in[3];
  const float* cm = (const float*)d_in[4];
  const float* Wk = (const float*)d_in[5];
  const float* Wv = (const float*)d_in[6];
  const float* Wr = (const float*)d_in[7];
  const float* Wo = (const float*)d_in[8];

  const size_t MC = (size_t)M_ROWS * C_DIM;        // 8,388,608
  const size_t CC = (size_t)C_DIM * C_DIM;         // 1,048,576

  char* ws = (char*)d_ws;
  ushort_t* xmb = (ushort_t*)ws; ws += MC * 2;
  ushort_t* Wb  = (ushort_t*)ws; ws += 4 * CC * 2;
  float*    kk  = (float*)ws;    ws += MC * 4;
  ushort_t* vv  = (ushort_t*)ws; ws += MC * 2;
  ushort_t* sr  = (ushort_t*)ws; ws += MC * 2;
  ushort_t* sy  = (ushort_t*)ws; ws += MC * 2;
  float* sa = (float*)ws; ws += (size_t)B_SZ * NCH * C_DIM * 4;
  float* sb = (float*)ws; ws += (size_t)B_SZ * NCH * C_DIM * 4;
  float* sp = (float*)ws; ws += (size_t)B_SZ * NCH * C_DIM * 4;

  cvt_w_kernel<<<(4 * CC) / 256, 256, 0, stream>>>(Wk, Wv, Wr, Wo, Wb);
  xm_kernel<<<MC / 256, 256, 0, stream>>>(x, tm, cm, xmb);

  dim3 gg(M_ROWS / 128, C_DIM / 128);
  gemm_bt<0><<<gg, 256, 0, stream>>>(xmb, Wb + 0 * CC, (void*)kk, M_ROWS, C_DIM, C_DIM);
  gemm_bt<1><<<gg, 256, 0, stream>>>(xmb, Wb + 1 * CC, (void*)vv, M_ROWS, C_DIM, C_DIM);
  gemm_bt<2><<<gg, 256, 0, stream>>>(xmb, Wb + 2 * CC, (void*)sr, M_ROWS, C_DIM, C_DIM);

  wkv_phaseA<<<(B_SZ * NCH * C_DIM) / 256, 256, 0, stream>>>(kk, vv, td, sa, sb, sp);
  wkv_phaseB<<<(B_SZ * C_DIM) / 256, 256, 0, stream>>>(td, sa, sb, sp);
  wkv_phaseC<<<(B_SZ * NCH * C_DIM) / 256, 256, 0, stream>>>(kk, vv, sr, td, tf, sa, sb, sp, sy);

  gemm_bt<3><<<gg, 256, 0, stream>>>(sy, Wb + 3 * CC, d_out, M_ROWS, C_DIM, C_DIM);
}

// Round 2
// 168.390 us; speedup vs baseline: 1.1105x; 1.1105x over previous
//
#include <hip/hip_runtime.h>
#include <hip/hip_bf16.h>
#include <stdint.h>

// Problem constants (match reference)
#define B_SZ 8
#define T_LEN 1024
#define C_DIM 1024
#define M_ROWS (B_SZ * T_LEN)   // 8192
#define NCH 32
#define CHL (T_LEN / NCH)       // 32

typedef unsigned short ushort_t;
typedef __attribute__((ext_vector_type(8))) short short8;
typedef __attribute__((ext_vector_type(4))) float f32x4;
typedef __attribute__((ext_vector_type(4))) unsigned short us4;

static __device__ __forceinline__ float bf2f(ushort_t u) {
  union { unsigned int i; float f; } x; x.i = ((unsigned int)u) << 16; return x.f;
}
static __device__ __forceinline__ ushort_t f2bf(float f) {
  union { float f; unsigned int i; } x; x.f = f;
  unsigned int r = x.i + 0x7fffu + ((x.i >> 16) & 1u);
  return (ushort_t)(r >> 16);
}

static __device__ __forceinline__ void gload_lds16(const void* g, void* l) {
  __builtin_amdgcn_global_load_lds(
      (const __attribute__((address_space(1))) void*)g,
      (__attribute__((address_space(3))) void*)l, 16, 0, 0);
}

// ---------------- weight f32 -> bf16 conversion (vectorized x4) ------------
__global__ void cvt_w_kernel(const float* __restrict__ wk, const float* __restrict__ wv,
                             const float* __restrict__ wr, const float* __restrict__ wo,
                             ushort_t* __restrict__ out) {
  int gid = blockIdx.x * 256 + threadIdx.x;       // 0 .. 4*2^20/4-1
  int which = gid >> 18;                          // element idx = gid*4; /2^20
  int off = (gid << 2) & ((1 << 20) - 1);
  const float* src = which == 0 ? wk : which == 1 ? wv : which == 2 ? wr : wo;
  float4 v = *(const float4*)(src + off);
  us4 o = {f2bf(v.x), f2bf(v.y), f2bf(v.z), f2bf(v.w)};
  *(us4*)(out + (size_t)gid * 4) = o;
}

// ---------------- time-shift mixing -> bf16 xm (vectorized x4) -------------
__global__ void xm_kernel(const float* __restrict__ x, const float* __restrict__ tm,
                          const float* __restrict__ cm, ushort_t* __restrict__ xmb) {
  int gid = blockIdx.x * 256 + threadIdx.x;       // over B*T*C/4
  int c4 = (gid & (C_DIM / 4 - 1)) * 4;
  int t = (gid >> 8) & (T_LEN - 1);
  const float4 zero = {0.f, 0.f, 0.f, 0.f};
  float4 xv = *(const float4*)(x + (size_t)gid * 4);
  float4 xp = (t > 0) ? *(const float4*)(x + (size_t)gid * 4 - C_DIM) : zero;
  float4 xn = (t < T_LEN - 1) ? *(const float4*)(x + (size_t)gid * 4 + C_DIM) : zero;
  float4 tmv = *(const float4*)(tm + c4);
  float4 cmv = *(const float4*)(cm + c4);
  // c4..c4+3 are all on one side of C/2 (c4 is a multiple of 4)
  float4 xc = (c4 < C_DIM / 2) ? xp : xn;
  us4 o;
  o.x = f2bf(xv.x * tmv.x + xp.x * (1.f - tmv.x) + xc.x * cmv.x);
  o.y = f2bf(xv.y * tmv.y + xp.y * (1.f - tmv.y) + xc.y * cmv.y);
  o.z = f2bf(xv.z * tmv.z + xp.z * (1.f - tmv.z) + xc.z * cmv.z);
  o.w = f2bf(xv.w * tmv.w + xp.w * (1.f - tmv.w) + xc.w * cmv.w);
  *(us4*)(xmb + (size_t)gid * 4) = o;
}

// ---------------- bf16 NT GEMM, dbuf + prefetch-overlap + slot swizzle -----
// FUSED=1: A=xmb, Bw = [Wk|Wv|Wr] (N=3072 logical), BN=128, grid (64,24).
//          column tile jb: mode = jb>>3 (0:kk f32 exp-clamp, 1:vv bf16,
//          2:sr bf16 sigmoid), local bn = (jb&7)*128.
// FUSED=0: output GEMM, BN=64, mode 3 -> f32 d_out, grid (64,16).
// LDS layout per operand: [rows][4 slots of 8 bf16]; physical slot =
// logical ^ ((row>>1)&3)  (read-side XOR; write-side applied by
// pre-swizzling the global SOURCE column while LDS dest stays linear —
// required because global_load_lds writes base+lane*16 linearly).
template <int FUSED, int BN>
__global__ __launch_bounds__(256) void gemm_bt(const ushort_t* __restrict__ A,
                                               const ushort_t* __restrict__ Bw,
                                               float* __restrict__ outF,
                                               ushort_t* __restrict__ outV,
                                               ushort_t* __restrict__ outR) {
  constexpr int K = 1024;
  constexpr int NT = K / 32;           // 32 K-steps
  constexpr int NF = BN / 32;          // n fragments per wave (4 or 2)
  __shared__ ushort_t As[2][128 * 32];
  __shared__ ushort_t Bs[2][BN * 32];

  const int tid = threadIdx.x;
  const int lane = tid & 63;
  const int wave = tid >> 6;
  const int bm = blockIdx.x * 128;
  const int jb = blockIdx.y;
  const int mode = FUSED ? (jb >> 3) : 3;
  const int bn = FUSED ? (jb & 7) * BN : jb * BN;
  const ushort_t* Bp = FUSED ? (Bw + ((size_t)(jb >> 3) << 20)) : Bw;

  const int wr = (wave >> 1) * 64;         // wave row offset
  const int wc = (wave & 1) * (BN / 2);    // wave col offset

  f32x4 acc[4][NF];
#pragma unroll
  for (int m = 0; m < 4; ++m)
#pragma unroll
    for (int n = 0; n < NF; ++n) acc[m][n] = (f32x4){0.f, 0.f, 0.f, 0.f};

  // staging addressing (pre-swizzled global source column)
  const int srow = tid >> 2;                         // 0..63
  const int scol = (((tid & 3) ^ ((srow >> 1) & 3)) * 8);
  const ushort_t* Ag = A + (size_t)(bm + srow) * K + scol;
  const ushort_t* Bg = Bp + (size_t)(bn + srow) * K + scol;
  ushort_t* AsP0 = &As[0][tid * 8];
  ushort_t* BsP0 = &Bs[0][tid * 8];
  ushort_t* AsP1 = &As[1][tid * 8];
  ushort_t* BsP1 = &Bs[1][tid * 8];

  // read addressing: lane (fr, kq); physical slot = kq ^ ((row>>1)&3);
  // rows are (mult of 16)+fr so ((row>>1)&3) == ((fr>>1)&3)
  const int fr = lane & 15;
  const int kq = lane >> 4;
  const int ps = (kq ^ ((fr >> 1) & 3)) * 8;

  auto stage = [&](int buf, int k0) {
    ushort_t* ap = buf ? AsP1 : AsP0;
    ushort_t* bp = buf ? BsP1 : BsP0;
    gload_lds16(Ag + k0, ap);
    gload_lds16(Ag + (size_t)64 * K + k0, ap + 64 * 32);
    gload_lds16(Bg + k0, bp);
    if (BN == 128) gload_lds16(Bg + (size_t)64 * K + k0, bp + 64 * 32);
  };

  stage(0, 0);
  asm volatile("s_waitcnt vmcnt(0)" ::: "memory");
  __syncthreads();

  int cur = 0;
  for (int t = 0; t < NT; ++t) {
    if (t < NT - 1) stage(cur ^ 1, (t + 1) * 32);
    short8 af[4], bfr[NF];
#pragma unroll
    for (int m = 0; m < 4; ++m)
      af[m] = *(const short8*)&As[cur][(wr + m * 16 + fr) * 32 + ps];
#pragma unroll
    for (int n = 0; n < NF; ++n)
      bfr[n] = *(const short8*)&Bs[cur][(wc + n * 16 + fr) * 32 + ps];
#pragma unroll
    for (int m = 0; m < 4; ++m)
#pragma unroll
      for (int n = 0; n < NF; ++n)
        acc[m][n] = __builtin_amdgcn_mfma_f32_16x16x32_bf16(af[m], bfr[n], acc[m][n], 0, 0, 0);
    asm volatile("s_waitcnt vmcnt(0)" ::: "memory");
    __syncthreads();
    cur ^= 1;
  }

  const int crow0 = (lane >> 4) * 4;   // C/D: col=lane&15, row=(lane>>4)*4+j
#pragma unroll
  for (int m = 0; m < 4; ++m)
#pragma unroll
    for (int n = 0; n < NF; ++n)
#pragma unroll
      for (int j = 0; j < 4; ++j) {
        float v = acc[m][n][j];
        size_t idx = (size_t)(bm + wr + m * 16 + crow0 + j) * C_DIM + (bn + wc + n * 16 + fr);
        if (mode == 0) {
          outF[idx] = __expf(fminf(v, 60.f));
        } else if (mode == 1) {
          outV[idx] = f2bf(v);
        } else if (mode == 2) {
          outR[idx] = f2bf(1.f / (1.f + __expf(-v)));
        } else {
          outF[idx] = v;
        }
      }
}

// ---------------- wkv chunked scan -----------------------------------------
// Phase A: per (b, chunk, c) compute chunk-local (a, b, p) from zero init.
__global__ void wkv_phaseA(const float* __restrict__ kk, const ushort_t* __restrict__ vv,
                           const float* __restrict__ td,
                           float* __restrict__ sa, float* __restrict__ sb,
                           float* __restrict__ sp) {
  int gid = blockIdx.x * 256 + threadIdx.x;   // b*NCH*C + ch*C + c
  int c = gid & (C_DIM - 1);
  int ch = (gid >> 10) & (NCH - 1);
  int b = gid >> 15;
  float w = td[c] * (1.f / T_LEN);
  size_t base = ((size_t)b * T_LEN + ch * CHL) * C_DIM + c;
  float a = 0.f, bb = 0.f, p = -1e38f;
  for (int t = 0; t < CHL; ++t) {
    float kt = kk[base + (size_t)t * C_DIM];
    float vt = bf2f(vv[base + (size_t)t * C_DIM]);
    float no2 = fmaxf(w + p, kt);
    float e1 = __expf(w + p - no2);
    float e2 = __expf(kt - no2);
    a = e1 * a + e2 * vt;
    bb = e1 * bb + e2;
    p = no2;
  }
  sa[gid] = a; sb[gid] = bb; sp[gid] = p;
}

// Phase B: per (b,c) serial prefix over the chunk states; overwrite each
// chunk slot with its INCOMING state (state before the chunk).
__global__ void wkv_phaseB(const float* __restrict__ td,
                           float* __restrict__ sa, float* __restrict__ sb,
                           float* __restrict__ sp) {
  int gid = blockIdx.x * 256 + threadIdx.x;   // b*C + c
  int c = gid & (C_DIM - 1);
  int b = gid >> 10;
  float wL = td[c] * (1.f / T_LEN) * (float)CHL;
  float a = 0.f, bb = 0.f, p = -1e38f;
  for (int ch = 0; ch < NCH; ++ch) {
    size_t idx = ((size_t)b * NCH + ch) * C_DIM + c;
    float ac = sa[idx], bc = sb[idx], pc = sp[idx];
    sa[idx] = a; sb[idx] = bb; sp[idx] = p;
    float pn = fmaxf(p + wL, pc);
    float e1 = __expf(p + wL - pn);
    float e2 = __expf(pc - pn);
    a = e1 * a + e2 * ac;
    bb = e1 * bb + e2 * bc;
    p = pn;
  }
}

// Phase C: per (b, chunk, c): rerun scan from incoming state, emit
// sy = bf16( sigmoid(r) * y ).
__global__ void wkv_phaseC(const float* __restrict__ kk, const ushort_t* __restrict__ vv,
                           const ushort_t* __restrict__ sr, const float* __restrict__ td,
                           const float* __restrict__ tf,
                           const float* __restrict__ sa, const float* __restrict__ sb,
                           const float* __restrict__ sp, ushort_t* __restrict__ sy) {
  int gid = blockIdx.x * 256 + threadIdx.x;
  int c = gid & (C_DIM - 1);
  int ch = (gid >> 10) & (NCH - 1);
  int b = gid >> 15;
  float w = td[c] * (1.f / T_LEN);
  float u = tf[c] * (1.f / T_LEN);
  size_t base = ((size_t)b * T_LEN + ch * CHL) * C_DIM + c;
  float a = sa[gid], bb = sb[gid], p = sp[gid];
  for (int t = 0; t < CHL; ++t) {
    float kt = kk[base + (size_t)t * C_DIM];
    float vt = bf2f(vv[base + (size_t)t * C_DIM]);
    float no = fmaxf(p, u + kt);
    float e1 = __expf(p - no);
    float e2 = __expf(u + kt - no);
    float y = (e1 * a + e2 * vt) / (e1 * bb + e2);
    float srv = bf2f(sr[base + (size_t)t * C_DIM]);
    sy[base + (size_t)t * C_DIM] = f2bf(srv * y);
    float no2 = fmaxf(w + p, kt);
    e1 = __expf(w + p - no2);
    e2 = __expf(kt - no2);
    a = e1 * a + e2 * vt;
    bb = e1 * bb + e2;
    p = no2;
  }
}

// ---------------------------------------------------------------------------
extern "C" void kernel_launch(void* const* d_in, const int* in_sizes, int n_in,
                              void* d_out, int out_size, void* d_ws, size_t ws_size,
                              hipStream_t stream) {
  const float* x  = (const float*)d_in[0];
  const float* td = (const float*)d_in[1];
  const float* tf = (const float*)d_in[2];
  const float* tm = (const float*)d_in[3];
  const float* cm = (const float*)d_in[4];
  const float* Wk = (const float*)d_in[5];
  const float* Wv = (const float*)d_in[6];
  const float* Wr = (const float*)d_in[7];
  const float* Wo = (const float*)d_in[8];

  const size_t MC = (size_t)M_ROWS * C_DIM;        // 8,388,608
  const size_t CC = (size_t)C_DIM * C_DIM;         // 1,048,576

  char* ws = (char*)d_ws;
  ushort_t* xmb = (ushort_t*)ws; ws += MC * 2;
  ushort_t* Wb  = (ushort_t*)ws; ws += 4 * CC * 2;
  float*    kk  = (float*)ws;    ws += MC * 4;
  ushort_t* vv  = (ushort_t*)ws; ws += MC * 2;
  ushort_t* sr  = (ushort_t*)ws; ws += MC * 2;
  ushort_t* sy  = (ushort_t*)ws; ws += MC * 2;
  float* sa = (float*)ws; ws += (size_t)B_SZ * NCH * C_DIM * 4;
  float* sb = (float*)ws; ws += (size_t)B_SZ * NCH * C_DIM * 4;
  float* sp = (float*)ws; ws += (size_t)B_SZ * NCH * C_DIM * 4;

  cvt_w_kernel<<<(4 * CC / 4) / 256, 256, 0, stream>>>(Wk, Wv, Wr, Wo, Wb);
  xm_kernel<<<(MC / 4) / 256, 256, 0, stream>>>(x, tm, cm, xmb);

  // fused k/v/r projections: N=3072, 1536 blocks
  gemm_bt<1, 128><<<dim3(M_ROWS / 128, 24), 256, 0, stream>>>(xmb, Wb, kk, vv, sr);

  wkv_phaseA<<<(B_SZ * NCH * C_DIM) / 256, 256, 0, stream>>>(kk, vv, td, sa, sb, sp);
  wkv_phaseB<<<(B_SZ * C_DIM) / 256, 256, 0, stream>>>(td, sa, sb, sp);
  wkv_phaseC<<<(B_SZ * NCH * C_DIM) / 256, 256, 0, stream>>>(kk, vv, sr, td, tf, sa, sb, sp, sy);

  // output projection: BN=64 -> 1024 blocks for occupancy
  gemm_bt<0, 64><<<dim3(M_ROWS / 128, 16), 256, 0, stream>>>(sy, Wb + 3 * CC, (float*)d_out, nullptr, nullptr);
}